// Round 4
// baseline (311.283 us; speedup 1.0000x reference)
//
#include <hip/hip_runtime.h>
#include <hip/hip_bf16.h>
#include <stdint.h>

// Workspace layout (bytes), total ~196 MB:
//  outbf  [0,        33554432)   out cast to bf16        (B*T*D)
//  vbf    [33554432, 67108864)   V = out @ W_write^T, bf16
//  wwbf   [67108864, 69206016)   W_write bf16
//  wrbf   [69206016, 71303168)   W_read  bf16
//  intra  [71303168, 104857600)  intra reads bf16 (flat B,T,D layout)
//  U      [104857600,138412032)  per-chunk outer products bf16 [BH][64][64*64]
//  Wst    [138412032,171966464)  per-chunk W states bf16  [BH][64][64*64]
//  reads  [171966464,205520896)  alpha*(inter+intra) bf16 (flat B,T,D)

typedef __bf16 bf16x8 __attribute__((ext_vector_type(8)));
typedef float f32x4 __attribute__((ext_vector_type(4)));

#define GAS __attribute__((address_space(1)))
#define LAS __attribute__((address_space(3)))

__device__ __forceinline__ unsigned short f2bf(float f) {
  unsigned u = __float_as_uint(f);
  u = (u + 0x7fffu + ((u >> 16) & 1u)) >> 16;   // RNE
  return (unsigned short)u;
}
__device__ __forceinline__ float bf2f(unsigned short h) {
  return __uint_as_float(((unsigned)h) << 16);
}

// ---------------------------------------------------------------- cast f32->bf16
__global__ __launch_bounds__(256) void cast_f32_to_bf16(
    const float* __restrict__ src, unsigned short* __restrict__ dst, int n8) {
  int i = blockIdx.x * 256 + threadIdx.x;  // handles 8 elements
  if (i >= n8) return;
  const float4* s = (const float4*)src + (size_t)i * 2;
  float4 f0 = s[0], f1 = s[1];
  union { uint4 u4; unsigned short us[8]; } o;
  o.us[0] = f2bf(f0.x); o.us[1] = f2bf(f0.y); o.us[2] = f2bf(f0.z); o.us[3] = f2bf(f0.w);
  o.us[4] = f2bf(f1.x); o.us[5] = f2bf(f1.y); o.us[6] = f2bf(f1.z); o.us[7] = f2bf(f1.w);
  ((uint4*)dst)[i] = o.u4;
}

// XCD-aware block swizzle for the 1024-block GEMMs (M/128=128 x N/128=8).
// XCD = id%8; XCD x owns bm rows == x (mod 8), bn sweeps fastest -> 4 MB A slice per XCD L2.
__device__ __forceinline__ void swizzle_bm_bn(int id, int& bm, int& bn) {
  int x = id & 7;
  int s = id >> 3;
  bn = s & 7;
  bm = ((s >> 3) << 3) | x;
}

// ---------------------------------------------------------------- GEMM C = A * B^T (bf16 out)
// A: M x K bf16 row-major, B: N x K bf16 row-major. 128x128 tile, BK=32, 4 waves.
// Register-staged pipeline, single 16 KB LDS buffer. The only barrier that can
// drain pending vmem is sync1 at the TOP of the iteration -- by then the loads
// (issued at the start of the previous compute phase) have had a full compute
// phase in flight. The compiler's vmcnt(0)-before-barrier policy costs ~nothing.
__global__ __launch_bounds__(256, 4) void gemm_bt_bf16out(
    const unsigned short* __restrict__ A, const unsigned short* __restrict__ B,
    unsigned short* __restrict__ C, int M, int N, int K) {
  __shared__ unsigned short As[128 * 32];
  __shared__ unsigned short Bs[128 * 32];
  int tid = threadIdx.x;
  int l = tid & 63, w = tid >> 6;
  int bm, bn;
  swizzle_bm_bn(blockIdx.x, bm, bn);
  int wm = (w >> 1) * 64, wn = (w & 1) * 64;
  f32x4 acc[4][4];
#pragma unroll
  for (int mi = 0; mi < 4; mi++)
#pragma unroll
    for (int ni = 0; ni < 4; ni++) acc[mi][ni] = (f32x4){0.f, 0.f, 0.f, 0.f};
  const unsigned short* Ab = A + (size_t)bm * 128 * K;
  const unsigned short* Bb = B + (size_t)bn * 128 * K;
  int lr = l >> 2, lc = (l & 3) * 8;
  int lm = l & 15, q4 = l >> 4;
  const int nit = K >> 5;
  // each wave stages rows [(w*2+q)*16 + lr], cols [lc, lc+8) ; LDS addr = (w*2+q)*512 + l*8
  int g0 = (w * 2 + 0) * 16 + lr, g1 = (w * 2 + 1) * 16 + lr;
  uint4 rA0, rA1, rB0, rB1;
  rA0 = *(const uint4*)(Ab + (size_t)g0 * K + lc);
  rA1 = *(const uint4*)(Ab + (size_t)g1 * K + lc);
  rB0 = *(const uint4*)(Bb + (size_t)g0 * K + lc);
  rB1 = *(const uint4*)(Bb + (size_t)g1 * K + lc);
  for (int it = 0; it < nit; it++) {
    __syncthreads();  // sync1: LDS consumers done; drains loads (had full compute phase)
    *(uint4*)&As[(w * 2 + 0) * 512 + l * 8] = rA0;
    *(uint4*)&As[(w * 2 + 1) * 512 + l * 8] = rA1;
    *(uint4*)&Bs[(w * 2 + 0) * 512 + l * 8] = rB0;
    *(uint4*)&Bs[(w * 2 + 1) * 512 + l * 8] = rB1;
    __syncthreads();  // sync2: LDS visible; no vmem pending -> no drain
    if (it + 1 < nit) {
      int k0 = (it + 1) << 5;
      rA0 = *(const uint4*)(Ab + (size_t)g0 * K + k0 + lc);
      rA1 = *(const uint4*)(Ab + (size_t)g1 * K + k0 + lc);
      rB0 = *(const uint4*)(Bb + (size_t)g0 * K + k0 + lc);
      rB1 = *(const uint4*)(Bb + (size_t)g1 * K + k0 + lc);
    }
    bf16x8 a[4], b[4];
#pragma unroll
    for (int mi = 0; mi < 4; mi++) a[mi] = *(const bf16x8*)&As[(wm + mi * 16 + lm) * 32 + q4 * 8];
#pragma unroll
    for (int ni = 0; ni < 4; ni++) b[ni] = *(const bf16x8*)&Bs[(wn + ni * 16 + lm) * 32 + q4 * 8];
#pragma unroll
    for (int mi = 0; mi < 4; mi++)
#pragma unroll
      for (int ni = 0; ni < 4; ni++)
        acc[mi][ni] = __builtin_amdgcn_mfma_f32_16x16x32_bf16(a[mi], b[ni], acc[mi][ni], 0, 0, 0);
  }
#pragma unroll
  for (int mi = 0; mi < 4; mi++)
#pragma unroll
    for (int ni = 0; ni < 4; ni++) {
      int r0 = bm * 128 + wm + mi * 16 + q4 * 4;
      int col = bn * 128 + wn + ni * 16 + lm;
#pragma unroll
      for (int j = 0; j < 4; j++)
        C[(size_t)(r0 + j) * N + col] = f2bf(acc[mi][ni][j]);
    }
}

// Same pipeline; C = base + A*B^T (fp32 out), base preloaded into accumulators.
__global__ __launch_bounds__(256, 4) void gemm_bt_addout(
    const unsigned short* __restrict__ A, const unsigned short* __restrict__ B,
    const float* __restrict__ base, float* __restrict__ C, int M, int N, int K) {
  __shared__ unsigned short As[128 * 32];
  __shared__ unsigned short Bs[128 * 32];
  int tid = threadIdx.x;
  int l = tid & 63, w = tid >> 6;
  int bm, bn;
  swizzle_bm_bn(blockIdx.x, bm, bn);
  int wm = (w >> 1) * 64, wn = (w & 1) * 64;
  int lr = l >> 2, lc = (l & 3) * 8;
  int lm = l & 15, q4 = l >> 4;
  f32x4 acc[4][4];
#pragma unroll
  for (int mi = 0; mi < 4; mi++)
#pragma unroll
    for (int ni = 0; ni < 4; ni++) {
      int r0 = bm * 128 + wm + mi * 16 + q4 * 4;
      int col = bn * 128 + wn + ni * 16 + lm;
#pragma unroll
      for (int j = 0; j < 4; j++)
        acc[mi][ni][j] = base[(size_t)(r0 + j) * N + col];
    }
  const unsigned short* Ab = A + (size_t)bm * 128 * K;
  const unsigned short* Bb = B + (size_t)bn * 128 * K;
  const int nit = K >> 5;
  int g0 = (w * 2 + 0) * 16 + lr, g1 = (w * 2 + 1) * 16 + lr;
  uint4 rA0, rA1, rB0, rB1;
  rA0 = *(const uint4*)(Ab + (size_t)g0 * K + lc);
  rA1 = *(const uint4*)(Ab + (size_t)g1 * K + lc);
  rB0 = *(const uint4*)(Bb + (size_t)g0 * K + lc);
  rB1 = *(const uint4*)(Bb + (size_t)g1 * K + lc);
  for (int it = 0; it < nit; it++) {
    __syncthreads();
    *(uint4*)&As[(w * 2 + 0) * 512 + l * 8] = rA0;
    *(uint4*)&As[(w * 2 + 1) * 512 + l * 8] = rA1;
    *(uint4*)&Bs[(w * 2 + 0) * 512 + l * 8] = rB0;
    *(uint4*)&Bs[(w * 2 + 1) * 512 + l * 8] = rB1;
    __syncthreads();
    if (it + 1 < nit) {
      int k0 = (it + 1) << 5;
      rA0 = *(const uint4*)(Ab + (size_t)g0 * K + k0 + lc);
      rA1 = *(const uint4*)(Ab + (size_t)g1 * K + k0 + lc);
      rB0 = *(const uint4*)(Bb + (size_t)g0 * K + k0 + lc);
      rB1 = *(const uint4*)(Bb + (size_t)g1 * K + k0 + lc);
    }
    bf16x8 a[4], b[4];
#pragma unroll
    for (int mi = 0; mi < 4; mi++) a[mi] = *(const bf16x8*)&As[(wm + mi * 16 + lm) * 32 + q4 * 8];
#pragma unroll
    for (int ni = 0; ni < 4; ni++) b[ni] = *(const bf16x8*)&Bs[(wn + ni * 16 + lm) * 32 + q4 * 8];
#pragma unroll
    for (int mi = 0; mi < 4; mi++)
#pragma unroll
      for (int ni = 0; ni < 4; ni++)
        acc[mi][ni] = __builtin_amdgcn_mfma_f32_16x16x32_bf16(a[mi], b[ni], acc[mi][ni], 0, 0, 0);
  }
#pragma unroll
  for (int mi = 0; mi < 4; mi++)
#pragma unroll
    for (int ni = 0; ni < 4; ni++) {
      int r0 = bm * 128 + wm + mi * 16 + q4 * 4;
      int col = bn * 128 + wn + ni * 16 + lm;
#pragma unroll
      for (int j = 0; j < 4; j++)
        C[(size_t)(r0 + j) * N + col] = acc[mi][ni][j];
    }
}

// ---------------------------------------------------------------- per-chunk local work
// grid (c=64, bh=64), 256 thr. Computes S=rk wk^T masked, intra=(S.M) v, U=(v*g_w)^T wk.
__global__ __launch_bounds__(256) void chunk_local(
    const unsigned short* __restrict__ rkg,   // outbf flat [B*T*D]
    const unsigned short* __restrict__ vg,    // vbf flat
    const float* __restrict__ decay,
    unsigned short* __restrict__ intra_bf,    // flat [B*T*D]
    unsigned short* __restrict__ U_bf) {      // [BH][64][64*64]
  int c = blockIdx.x, bh = blockIdx.y;
  int b = bh >> 4, h = bh & 15;
  int tid = threadIdx.x, l = tid & 63, w = tid >> 6;
  float gamma = 1.0f / (1.0f + __expf(-decay[h]));
  float lg = __logf(gamma);

  // stride-72 padding: keeps 16B alignment for uint4/b128 and spreads banks
  __shared__ unsigned short rk_s[64 * 72];
  __shared__ unsigned short wk_s[64 * 72];
  __shared__ unsigned short wkT_s[64 * 72];
  __shared__ unsigned short vT_s[64 * 72];
  __shared__ unsigned short S_s[64 * 72];

  const size_t rowbase = (((size_t)b * 4096 + (size_t)c * 64) * 1024) + h * 64;

#pragma unroll
  for (int r = 0; r < 2; r++) {
    int e = r * 256 + tid;
    int p = e >> 3, seg = e & 7;
    uint4 dr = *(const uint4*)(rkg + rowbase + (size_t)p * 1024 + seg * 8);
    *(uint4*)&rk_s[p * 72 + seg * 8] = dr;
    uint4 dv = *(const uint4*)(vg + rowbase + (size_t)p * 1024 + seg * 8);
    {
      unsigned uu[4] = {dv.x, dv.y, dv.z, dv.w};
#pragma unroll
      for (int qq = 0; qq < 4; qq++) {
        vT_s[(seg * 8 + qq * 2) * 72 + p] = (unsigned short)(uu[qq] & 0xffffu);
        vT_s[(seg * 8 + qq * 2 + 1) * 72 + p] = (unsigned short)(uu[qq] >> 16);
      }
    }
    int tg = c * 64 + p - 1;  // wk = rk shifted right by one token (zero at t=0)
    uint4 dw = make_uint4(0u, 0u, 0u, 0u);
    if (tg >= 0) dw = *(const uint4*)(rkg + ((size_t)b * 4096 + tg) * 1024 + h * 64 + seg * 8);
    *(uint4*)&wk_s[p * 72 + seg * 8] = dw;
    {
      unsigned uu[4] = {dw.x, dw.y, dw.z, dw.w};
#pragma unroll
      for (int qq = 0; qq < 4; qq++) {
        wkT_s[(seg * 8 + qq * 2) * 72 + p] = (unsigned short)(uu[qq] & 0xffffu);
        wkT_s[(seg * 8 + qq * 2 + 1) * 72 + p] = (unsigned short)(uu[qq] >> 16);
      }
    }
  }
  __syncthreads();

  int lm = l & 15, q4 = l >> 4;

  // Phase 1: S = rk @ wk^T, apply mask M, store bf16
  {
    bf16x8 a0 = *(const bf16x8*)&rk_s[(w * 16 + lm) * 72 + q4 * 8];
    bf16x8 a1 = *(const bf16x8*)&rk_s[(w * 16 + lm) * 72 + 32 + q4 * 8];
#pragma unroll
    for (int ni = 0; ni < 4; ni++) {
      bf16x8 b0 = *(const bf16x8*)&wk_s[(ni * 16 + lm) * 72 + q4 * 8];
      bf16x8 b1 = *(const bf16x8*)&wk_s[(ni * 16 + lm) * 72 + 32 + q4 * 8];
      f32x4 acc = {0.f, 0.f, 0.f, 0.f};
      acc = __builtin_amdgcn_mfma_f32_16x16x32_bf16(a0, b0, acc, 0, 0, 0);
      acc = __builtin_amdgcn_mfma_f32_16x16x32_bf16(a1, b1, acc, 0, 0, 0);
#pragma unroll
      for (int j = 0; j < 4; j++) {
        int p = w * 16 + q4 * 4 + j;
        int q = ni * 16 + lm;
        float m = (p > q) ? __expf(lg * (float)(p - 1 - q)) : 0.0f;
        S_s[p * 72 + q] = f2bf(acc[j] * m);
      }
    }
  }
  __syncthreads();

  // Phase 2: intra = (S.M) @ v   (B operand from vT rows)
  {
    bf16x8 a0 = *(const bf16x8*)&S_s[(w * 16 + lm) * 72 + q4 * 8];
    bf16x8 a1 = *(const bf16x8*)&S_s[(w * 16 + lm) * 72 + 32 + q4 * 8];
#pragma unroll
    for (int ni = 0; ni < 4; ni++) {
      bf16x8 b0 = *(const bf16x8*)&vT_s[(ni * 16 + lm) * 72 + q4 * 8];
      bf16x8 b1 = *(const bf16x8*)&vT_s[(ni * 16 + lm) * 72 + 32 + q4 * 8];
      f32x4 acc = {0.f, 0.f, 0.f, 0.f};
      acc = __builtin_amdgcn_mfma_f32_16x16x32_bf16(a0, b0, acc, 0, 0, 0);
      acc = __builtin_amdgcn_mfma_f32_16x16x32_bf16(a1, b1, acc, 0, 0, 0);
#pragma unroll
      for (int j = 0; j < 4; j++) {
        int p = w * 16 + q4 * 4 + j;
        int i = ni * 16 + lm;
        intra_bf[rowbase + (size_t)p * 1024 + i] = f2bf(acc[j]);
      }
    }
  }

  // Phase 3: U = (v * g_w)^T @ wk   (A from vT scaled by gamma^(63-p), B from wkT)
  {
    bf16x8 a0 = *(const bf16x8*)&vT_s[(w * 16 + lm) * 72 + q4 * 8];
    bf16x8 a1 = *(const bf16x8*)&vT_s[(w * 16 + lm) * 72 + 32 + q4 * 8];
#pragma unroll
    for (int jj = 0; jj < 8; jj++) {
      int p0 = q4 * 8 + jj;
      a0[jj] = (__bf16)((float)a0[jj] * __expf(lg * (float)(63 - p0)));
      a1[jj] = (__bf16)((float)a1[jj] * __expf(lg * (float)(63 - (p0 + 32))));
    }
    size_t ub = ((size_t)bh * 64 + c) * 4096;
#pragma unroll
    for (int nj = 0; nj < 4; nj++) {
      bf16x8 b0 = *(const bf16x8*)&wkT_s[(nj * 16 + lm) * 72 + q4 * 8];
      bf16x8 b1 = *(const bf16x8*)&wkT_s[(nj * 16 + lm) * 72 + 32 + q4 * 8];
      f32x4 acc = {0.f, 0.f, 0.f, 0.f};
      acc = __builtin_amdgcn_mfma_f32_16x16x32_bf16(a0, b0, acc, 0, 0, 0);
      acc = __builtin_amdgcn_mfma_f32_16x16x32_bf16(a1, b1, acc, 0, 0, 0);
#pragma unroll
      for (int j = 0; j < 4; j++) {
        int i = w * 16 + q4 * 4 + j;
        int col = nj * 16 + lm;
        U_bf[ub + i * 64 + col] = f2bf(acc[j]);
      }
    }
  }
}

// ---------------------------------------------------------------- parallel chunk-scan as matmul
// Wst[bh][c][n] = sum_k L[c,k] * U[bh][k][n], L[c,k] = gC^(c-1-k) for k<c else 0.
// grid (ntile=32, bh=64), 256 thr; each block: M=64 (chunks) x N=128 cols x K=64.
__global__ __launch_bounds__(256) void scan_matmul(
    const unsigned short* __restrict__ U_bf, unsigned short* __restrict__ Wst,
    const float* __restrict__ decay) {
  int col0 = blockIdx.x * 128, bh = blockIdx.y, h = bh & 15;
  int tid = threadIdx.x, l = tid & 63, w = tid >> 6;
  float gamma = 1.0f / (1.0f + __expf(-decay[h]));
  float lgC = 64.0f * __logf(gamma);   // ln(gamma^64)

  __shared__ unsigned short L_s[64 * 72];
  __shared__ unsigned short B_s[128 * 72];

  // build L: thread covers row m=tid>>2, k in [(tid&3)*16, +16)
  {
    int m = tid >> 2, kk0 = (tid & 3) * 16;
#pragma unroll
    for (int e = 0; e < 16; e++) {
      int k = kk0 + e;
      float v = (k < m) ? __expf(lgC * (float)(m - 1 - k)) : 0.0f;
      L_s[m * 72 + k] = f2bf(v);
    }
  }
  // load U tile [64 k x 128 n], transpose into B_s[n][k]
  size_t ub = (size_t)bh * 64 * 4096 + col0;
#pragma unroll
  for (int it = 0; it < 4; it++) {
    int e = it * 256 + tid;      // 1024 uint4 loads
    int k = e >> 4, seg = e & 15;
    uint4 d = *(const uint4*)(U_bf + ub + (size_t)k * 4096 + seg * 8);
    unsigned uu[4] = {d.x, d.y, d.z, d.w};
#pragma unroll
    for (int qq = 0; qq < 4; qq++) {
      B_s[(seg * 8 + qq * 2) * 72 + k] = (unsigned short)(uu[qq] & 0xffffu);
      B_s[(seg * 8 + qq * 2 + 1) * 72 + k] = (unsigned short)(uu[qq] >> 16);
    }
  }
  __syncthreads();

  int lm = l & 15, q4 = l >> 4;
  // wave w: n-slice [w*32, w*32+32)
  f32x4 acc[4][2];
#pragma unroll
  for (int mi = 0; mi < 4; mi++)
#pragma unroll
    for (int ni = 0; ni < 2; ni++) acc[mi][ni] = (f32x4){0.f, 0.f, 0.f, 0.f};
#pragma unroll
  for (int kk = 0; kk < 2; kk++) {
    bf16x8 a[4], b[2];
#pragma unroll
    for (int mi = 0; mi < 4; mi++)
      a[mi] = *(const bf16x8*)&L_s[(mi * 16 + lm) * 72 + kk * 32 + q4 * 8];
#pragma unroll
    for (int ni = 0; ni < 2; ni++)
      b[ni] = *(const bf16x8*)&B_s[(w * 32 + ni * 16 + lm) * 72 + kk * 32 + q4 * 8];
#pragma unroll
    for (int mi = 0; mi < 4; mi++)
#pragma unroll
      for (int ni = 0; ni < 2; ni++)
        acc[mi][ni] = __builtin_amdgcn_mfma_f32_16x16x32_bf16(a[mi], b[ni], acc[mi][ni], 0, 0, 0);
  }
  size_t wb = (size_t)bh * 64 * 4096 + col0;
#pragma unroll
  for (int mi = 0; mi < 4; mi++)
#pragma unroll
    for (int ni = 0; ni < 2; ni++)
#pragma unroll
      for (int j = 0; j < 4; j++) {
        int c = mi * 16 + q4 * 4 + j;
        int n = w * 32 + ni * 16 + lm;
        Wst[wb + (size_t)c * 4096 + n] = f2bf(acc[mi][ni][j]);
      }
}

// ---------------------------------------------------------------- inter reads + combine
// grid (c=64, bh=64): inter = g_p * (W_c @ rk^T)^T ; reads = alpha*(inter+intra) -> bf16
__global__ __launch_bounds__(256) void inter_combine(
    const unsigned short* __restrict__ rkg, const unsigned short* __restrict__ Wst,
    const unsigned short* __restrict__ intra_bf,
    const float* __restrict__ decay, const float* __restrict__ log_alpha,
    unsigned short* __restrict__ reads_bf) {
  int c = blockIdx.x, bh = blockIdx.y;
  int b = bh >> 4, h = bh & 15;
  int tid = threadIdx.x, l = tid & 63, w = tid >> 6;
  float gamma = 1.0f / (1.0f + __expf(-decay[h]));
  float lg = __logf(gamma);
  float alpha = __expf(log_alpha[h]);
  __shared__ unsigned short rk_s[64 * 72];
  __shared__ unsigned short W_s[64 * 72];
  const size_t rowbase = (((size_t)b * 4096 + (size_t)c * 64) * 1024) + h * 64;
  size_t wbase = ((size_t)bh * 64 + c) * 4096;
#pragma unroll
  for (int r = 0; r < 2; r++) {
    int e = r * 256 + tid;
    int p = e >> 3, seg = e & 7;
    *(uint4*)&rk_s[p * 72 + seg * 8] = *(const uint4*)(rkg + rowbase + (size_t)p * 1024 + seg * 8);
    *(uint4*)&W_s[p * 72 + seg * 8] = *(const uint4*)(Wst + wbase + (size_t)e * 8);
  }
  __syncthreads();
  int lm = l & 15, q4 = l >> 4;
  bf16x8 a0 = *(const bf16x8*)&rk_s[(w * 16 + lm) * 72 + q4 * 8];
  bf16x8 a1 = *(const bf16x8*)&rk_s[(w * 16 + lm) * 72 + 32 + q4 * 8];
#pragma unroll
  for (int ni = 0; ni < 4; ni++) {
    bf16x8 b0 = *(const bf16x8*)&W_s[(ni * 16 + lm) * 72 + q4 * 8];
    bf16x8 b1 = *(const bf16x8*)&W_s[(ni * 16 + lm) * 72 + 32 + q4 * 8];
    f32x4 acc = {0.f, 0.f, 0.f, 0.f};
    acc = __builtin_amdgcn_mfma_f32_16x16x32_bf16(a0, b0, acc, 0, 0, 0);
    acc = __builtin_amdgcn_mfma_f32_16x16x32_bf16(a1, b1, acc, 0, 0, 0);
#pragma unroll
    for (int j = 0; j < 4; j++) {
      int p = w * 16 + q4 * 4 + j;
      int i = ni * 16 + lm;
      float gp = __expf(lg * (float)p);
      size_t ad = rowbase + (size_t)p * 1024 + i;
      reads_bf[ad] = f2bf(alpha * (acc[j] * gp + bf2f(intra_bf[ad])));
    }
  }
}

// ----------------------------------------------------------------
extern "C" void kernel_launch(void* const* d_in, const int* in_sizes, int n_in,
                              void* d_out, int out_size, void* d_ws, size_t ws_size,
                              hipStream_t stream) {
  const float* out_f = (const float*)d_in[0];
  const float* Ww = (const float*)d_in[1];
  const float* Wr = (const float*)d_in[2];
  const float* decay = (const float*)d_in[3];
  const float* lalpha = (const float*)d_in[4];

  char* ws = (char*)d_ws;
  unsigned short* outbf = (unsigned short*)(ws + 0);
  unsigned short* vbf   = (unsigned short*)(ws + 33554432);
  unsigned short* wwbf  = (unsigned short*)(ws + 67108864);
  unsigned short* wrbf  = (unsigned short*)(ws + 69206016);
  unsigned short* intra = (unsigned short*)(ws + 71303168);
  unsigned short* U     = (unsigned short*)(ws + 104857600);
  unsigned short* Wst   = (unsigned short*)(ws + 138412032);
  unsigned short* reads = (unsigned short*)(ws + 171966464);

  cast_f32_to_bf16<<<dim3(8192), 256, 0, stream>>>(out_f, outbf, 16777216 / 8);
  cast_f32_to_bf16<<<dim3(512), 256, 0, stream>>>(Ww, wwbf, 1048576 / 8);
  cast_f32_to_bf16<<<dim3(512), 256, 0, stream>>>(Wr, wrbf, 1048576 / 8);

  // V = out @ W_write^T   (M=B*T=16384, N=D=1024, K=D=1024)
  gemm_bt_bf16out<<<dim3(1024), 256, 0, stream>>>(outbf, wwbf, vbf, 16384, 1024, 1024);

  chunk_local<<<dim3(64, 64), 256, 0, stream>>>(outbf, vbf, decay, intra, U);
  scan_matmul<<<dim3(32, 64), 256, 0, stream>>>(U, Wst, decay);
  inter_combine<<<dim3(64, 64), 256, 0, stream>>>(outbf, Wst, intra, decay, lalpha, reads);

  // final = out + reads @ W_read^T
  gemm_bt_addout<<<dim3(1024), 256, 0, stream>>>(reads, wrbf, out_f, (float*)d_out,
                                                 16384, 1024, 1024);
}

// Round 5
// 297.500 us; speedup vs baseline: 1.0463x; 1.0463x over previous
//
#include <hip/hip_runtime.h>
#include <hip/hip_bf16.h>
#include <stdint.h>

// Workspace layout (bytes):
//  outbf  [0,        33554432)   out cast to bf16        (B*T*D)
//  vbf    [33554432, 67108864)   V = out @ W_write^T, bf16
//  wwbf   [67108864, 69206016)   W_write bf16
//  wrbf   [69206016, 71303168)   W_read  bf16
//  intra  [71303168, 104857600)  intra reads bf16 (flat B,T,D layout)
//  U      [104857600,138412032)  per-chunk outer products bf16 [BH][64][64*64]
//  reads  [171966464,205520896)  alpha*(inter+intra) bf16 (flat B,T,D)

typedef __bf16 bf16x8 __attribute__((ext_vector_type(8)));
typedef float f32x4 __attribute__((ext_vector_type(4)));

#define GAS __attribute__((address_space(1)))
#define LAS __attribute__((address_space(3)))

__device__ __forceinline__ unsigned short f2bf(float f) {
  unsigned u = __float_as_uint(f);
  u = (u + 0x7fffu + ((u >> 16) & 1u)) >> 16;   // RNE
  return (unsigned short)u;
}
__device__ __forceinline__ float bf2f(unsigned short h) {
  return __uint_as_float(((unsigned)h) << 16);
}

// ---------------------------------------------------------------- cast f32->bf16
__global__ __launch_bounds__(256) void cast_f32_to_bf16(
    const float* __restrict__ src, unsigned short* __restrict__ dst, int n8) {
  int i = blockIdx.x * 256 + threadIdx.x;  // handles 8 elements
  if (i >= n8) return;
  const float4* s = (const float4*)src + (size_t)i * 2;
  float4 f0 = s[0], f1 = s[1];
  union { uint4 u4; unsigned short us[8]; } o;
  o.us[0] = f2bf(f0.x); o.us[1] = f2bf(f0.y); o.us[2] = f2bf(f0.z); o.us[3] = f2bf(f0.w);
  o.us[4] = f2bf(f1.x); o.us[5] = f2bf(f1.y); o.us[6] = f2bf(f1.z); o.us[7] = f2bf(f1.w);
  ((uint4*)dst)[i] = o.u4;
}

// both 1024x1024 weights in one launch: i8 < 131072 -> W_write, else W_read
__global__ __launch_bounds__(256) void cast_weights(
    const float* __restrict__ w1, const float* __restrict__ w2,
    unsigned short* __restrict__ dst) {
  int i = blockIdx.x * 256 + threadIdx.x;  // 262144 total (2*1048576/8)
  const float* src = (i < 131072) ? w1 : w2;
  int j = (i < 131072) ? i : i - 131072;
  const float4* s = (const float4*)src + (size_t)j * 2;
  float4 f0 = s[0], f1 = s[1];
  union { uint4 u4; unsigned short us[8]; } o;
  o.us[0] = f2bf(f0.x); o.us[1] = f2bf(f0.y); o.us[2] = f2bf(f0.z); o.us[3] = f2bf(f0.w);
  o.us[4] = f2bf(f1.x); o.us[5] = f2bf(f1.y); o.us[6] = f2bf(f1.z); o.us[7] = f2bf(f1.w);
  ((uint4*)dst)[i] = o.u4;
}

// XCD-aware block swizzle for the 1024-block GEMMs (M/128=128 x N/128=8).
// XCD = id%8; XCD x owns bm rows == x (mod 8), bn sweeps fastest -> 4 MB A slice per XCD L2.
__device__ __forceinline__ void swizzle_bm_bn(int id, int& bm, int& bn) {
  int x = id & 7;
  int s = id >> 3;
  bn = s & 7;
  bm = ((s >> 3) << 3) | x;
}

// ---------------------------------------------------------------- GEMM C = A * B^T (bf16 out)
// R3 structure (best known): glds width=16, double-buffered 2x16KB LDS, one barrier
// per iter placed BEFORE next-tile issue. __launch_bounds__(256,4) -> one resident round.
__global__ __launch_bounds__(256, 4) void gemm_bt_bf16out(
    const unsigned short* __restrict__ A, const unsigned short* __restrict__ B,
    unsigned short* __restrict__ C, int M, int N, int K) {
  __shared__ unsigned short As[2][128 * 32];
  __shared__ unsigned short Bs[2][128 * 32];
  int tid = threadIdx.x;
  int l = tid & 63, w = tid >> 6;
  int bm, bn;
  swizzle_bm_bn(blockIdx.x, bm, bn);
  int wm = (w >> 1) * 64, wn = (w & 1) * 64;
  f32x4 acc[4][4];
#pragma unroll
  for (int mi = 0; mi < 4; mi++)
#pragma unroll
    for (int ni = 0; ni < 4; ni++) acc[mi][ni] = (f32x4){0.f, 0.f, 0.f, 0.f};
  const unsigned short* Ab = A + (size_t)bm * 128 * K;
  const unsigned short* Bb = B + (size_t)bn * 128 * K;
  int lr = l >> 2, lc = (l & 3) * 8;
  int lm = l & 15, q4 = l >> 4;
  const int nit = K >> 5;
#pragma unroll
  for (int q = 0; q < 2; q++) {
    int g = (w * 2 + q) * 16 + lr;
    __builtin_amdgcn_global_load_lds((GAS void*)(void*)(Ab + (size_t)g * K + lc),
                                     (LAS void*)(&As[0][(w * 2 + q) * 512]), 16, 0, 0);
    __builtin_amdgcn_global_load_lds((GAS void*)(void*)(Bb + (size_t)g * K + lc),
                                     (LAS void*)(&Bs[0][(w * 2 + q) * 512]), 16, 0, 0);
  }
  for (int it = 0; it < nit; it++) {
    __syncthreads();
    int buf = it & 1;
    if (it + 1 < nit) {
      int k0 = (it + 1) << 5;
#pragma unroll
      for (int q = 0; q < 2; q++) {
        int g = (w * 2 + q) * 16 + lr;
        __builtin_amdgcn_global_load_lds((GAS void*)(void*)(Ab + (size_t)g * K + k0 + lc),
                                         (LAS void*)(&As[buf ^ 1][(w * 2 + q) * 512]), 16, 0, 0);
        __builtin_amdgcn_global_load_lds((GAS void*)(void*)(Bb + (size_t)g * K + k0 + lc),
                                         (LAS void*)(&Bs[buf ^ 1][(w * 2 + q) * 512]), 16, 0, 0);
      }
    }
    bf16x8 a[4], b[4];
#pragma unroll
    for (int mi = 0; mi < 4; mi++) a[mi] = *(const bf16x8*)&As[buf][(wm + mi * 16 + lm) * 32 + q4 * 8];
#pragma unroll
    for (int ni = 0; ni < 4; ni++) b[ni] = *(const bf16x8*)&Bs[buf][(wn + ni * 16 + lm) * 32 + q4 * 8];
#pragma unroll
    for (int mi = 0; mi < 4; mi++)
#pragma unroll
      for (int ni = 0; ni < 4; ni++)
        acc[mi][ni] = __builtin_amdgcn_mfma_f32_16x16x32_bf16(a[mi], b[ni], acc[mi][ni], 0, 0, 0);
  }
#pragma unroll
  for (int mi = 0; mi < 4; mi++)
#pragma unroll
    for (int ni = 0; ni < 4; ni++) {
      int r0 = bm * 128 + wm + mi * 16 + q4 * 4;
      int col = bn * 128 + wn + ni * 16 + lm;
#pragma unroll
      for (int j = 0; j < 4; j++)
        C[(size_t)(r0 + j) * N + col] = f2bf(acc[mi][ni][j]);
    }
}

// Same structure; C = base(bf16) + A*B^T (fp32 out). base preloaded into accumulators
// (bf16 halves the base fetch; error <= ~0.01 abs, well within threshold margin).
__global__ __launch_bounds__(256, 4) void gemm_bt_addout(
    const unsigned short* __restrict__ A, const unsigned short* __restrict__ B,
    const unsigned short* __restrict__ base_bf, float* __restrict__ C, int M, int N, int K) {
  __shared__ unsigned short As[2][128 * 32];
  __shared__ unsigned short Bs[2][128 * 32];
  int tid = threadIdx.x;
  int l = tid & 63, w = tid >> 6;
  int bm, bn;
  swizzle_bm_bn(blockIdx.x, bm, bn);
  int wm = (w >> 1) * 64, wn = (w & 1) * 64;
  int lr = l >> 2, lc = (l & 3) * 8;
  int lm = l & 15, q4 = l >> 4;
  f32x4 acc[4][4];
#pragma unroll
  for (int mi = 0; mi < 4; mi++)
#pragma unroll
    for (int ni = 0; ni < 4; ni++) {
      int r0 = bm * 128 + wm + mi * 16 + q4 * 4;
      int col = bn * 128 + wn + ni * 16 + lm;
#pragma unroll
      for (int j = 0; j < 4; j++)
        acc[mi][ni][j] = bf2f(base_bf[(size_t)(r0 + j) * N + col]);
    }
  const unsigned short* Ab = A + (size_t)bm * 128 * K;
  const unsigned short* Bb = B + (size_t)bn * 128 * K;
  const int nit = K >> 5;
#pragma unroll
  for (int q = 0; q < 2; q++) {
    int g = (w * 2 + q) * 16 + lr;
    __builtin_amdgcn_global_load_lds((GAS void*)(void*)(Ab + (size_t)g * K + lc),
                                     (LAS void*)(&As[0][(w * 2 + q) * 512]), 16, 0, 0);
    __builtin_amdgcn_global_load_lds((GAS void*)(void*)(Bb + (size_t)g * K + lc),
                                     (LAS void*)(&Bs[0][(w * 2 + q) * 512]), 16, 0, 0);
  }
  for (int it = 0; it < nit; it++) {
    __syncthreads();
    int buf = it & 1;
    if (it + 1 < nit) {
      int k0 = (it + 1) << 5;
#pragma unroll
      for (int q = 0; q < 2; q++) {
        int g = (w * 2 + q) * 16 + lr;
        __builtin_amdgcn_global_load_lds((GAS void*)(void*)(Ab + (size_t)g * K + k0 + lc),
                                         (LAS void*)(&As[buf ^ 1][(w * 2 + q) * 512]), 16, 0, 0);
        __builtin_amdgcn_global_load_lds((GAS void*)(void*)(Bb + (size_t)g * K + k0 + lc),
                                         (LAS void*)(&Bs[buf ^ 1][(w * 2 + q) * 512]), 16, 0, 0);
      }
    }
    bf16x8 a[4], b[4];
#pragma unroll
    for (int mi = 0; mi < 4; mi++) a[mi] = *(const bf16x8*)&As[buf][(wm + mi * 16 + lm) * 32 + q4 * 8];
#pragma unroll
    for (int ni = 0; ni < 4; ni++) b[ni] = *(const bf16x8*)&Bs[buf][(wn + ni * 16 + lm) * 32 + q4 * 8];
#pragma unroll
    for (int mi = 0; mi < 4; mi++)
#pragma unroll
      for (int ni = 0; ni < 4; ni++)
        acc[mi][ni] = __builtin_amdgcn_mfma_f32_16x16x32_bf16(a[mi], b[ni], acc[mi][ni], 0, 0, 0);
  }
#pragma unroll
  for (int mi = 0; mi < 4; mi++)
#pragma unroll
    for (int ni = 0; ni < 4; ni++) {
      int r0 = bm * 128 + wm + mi * 16 + q4 * 4;
      int col = bn * 128 + wn + ni * 16 + lm;
#pragma unroll
      for (int j = 0; j < 4; j++)
        C[(size_t)(r0 + j) * N + col] = acc[mi][ni][j];
    }
}

// ---------------------------------------------------------------- per-chunk local work
// grid (c=64, bh=64), 256 thr. Computes S=rk wk^T masked, intra=(S.M) v, U=(v*g_w)^T wk.
__global__ __launch_bounds__(256) void chunk_local(
    const unsigned short* __restrict__ rkg,   // outbf flat [B*T*D]
    const unsigned short* __restrict__ vg,    // vbf flat
    const float* __restrict__ decay,
    unsigned short* __restrict__ intra_bf,    // flat [B*T*D]
    unsigned short* __restrict__ U_bf) {      // [BH][64][64*64]
  int c = blockIdx.x, bh = blockIdx.y;
  int b = bh >> 4, h = bh & 15;
  int tid = threadIdx.x, l = tid & 63, w = tid >> 6;
  float gamma = 1.0f / (1.0f + __expf(-decay[h]));
  float lg = __logf(gamma);

  __shared__ unsigned short rk_s[64 * 72];
  __shared__ unsigned short wk_s[64 * 72];
  __shared__ unsigned short wkT_s[64 * 72];
  __shared__ unsigned short vT_s[64 * 72];
  __shared__ unsigned short S_s[64 * 72];

  const size_t rowbase = (((size_t)b * 4096 + (size_t)c * 64) * 1024) + h * 64;

#pragma unroll
  for (int r = 0; r < 2; r++) {
    int e = r * 256 + tid;
    int p = e >> 3, seg = e & 7;
    uint4 dr = *(const uint4*)(rkg + rowbase + (size_t)p * 1024 + seg * 8);
    *(uint4*)&rk_s[p * 72 + seg * 8] = dr;
    uint4 dv = *(const uint4*)(vg + rowbase + (size_t)p * 1024 + seg * 8);
    {
      unsigned uu[4] = {dv.x, dv.y, dv.z, dv.w};
#pragma unroll
      for (int qq = 0; qq < 4; qq++) {
        vT_s[(seg * 8 + qq * 2) * 72 + p] = (unsigned short)(uu[qq] & 0xffffu);
        vT_s[(seg * 8 + qq * 2 + 1) * 72 + p] = (unsigned short)(uu[qq] >> 16);
      }
    }
    int tg = c * 64 + p - 1;  // wk = rk shifted right by one token (zero at t=0)
    uint4 dw = make_uint4(0u, 0u, 0u, 0u);
    if (tg >= 0) dw = *(const uint4*)(rkg + ((size_t)b * 4096 + tg) * 1024 + h * 64 + seg * 8);
    *(uint4*)&wk_s[p * 72 + seg * 8] = dw;
    {
      unsigned uu[4] = {dw.x, dw.y, dw.z, dw.w};
#pragma unroll
      for (int qq = 0; qq < 4; qq++) {
        wkT_s[(seg * 8 + qq * 2) * 72 + p] = (unsigned short)(uu[qq] & 0xffffu);
        wkT_s[(seg * 8 + qq * 2 + 1) * 72 + p] = (unsigned short)(uu[qq] >> 16);
      }
    }
  }
  __syncthreads();

  int lm = l & 15, q4 = l >> 4;

  // Phase 1: S = rk @ wk^T, apply mask M, store bf16
  {
    bf16x8 a0 = *(const bf16x8*)&rk_s[(w * 16 + lm) * 72 + q4 * 8];
    bf16x8 a1 = *(const bf16x8*)&rk_s[(w * 16 + lm) * 72 + 32 + q4 * 8];
#pragma unroll
    for (int ni = 0; ni < 4; ni++) {
      bf16x8 b0 = *(const bf16x8*)&wk_s[(ni * 16 + lm) * 72 + q4 * 8];
      bf16x8 b1 = *(const bf16x8*)&wk_s[(ni * 16 + lm) * 72 + 32 + q4 * 8];
      f32x4 acc = {0.f, 0.f, 0.f, 0.f};
      acc = __builtin_amdgcn_mfma_f32_16x16x32_bf16(a0, b0, acc, 0, 0, 0);
      acc = __builtin_amdgcn_mfma_f32_16x16x32_bf16(a1, b1, acc, 0, 0, 0);
#pragma unroll
      for (int j = 0; j < 4; j++) {
        int p = w * 16 + q4 * 4 + j;
        int q = ni * 16 + lm;
        float m = (p > q) ? __expf(lg * (float)(p - 1 - q)) : 0.0f;
        S_s[p * 72 + q] = f2bf(acc[j] * m);
      }
    }
  }
  __syncthreads();

  // Phase 2: intra = (S.M) @ v
  {
    bf16x8 a0 = *(const bf16x8*)&S_s[(w * 16 + lm) * 72 + q4 * 8];
    bf16x8 a1 = *(const bf16x8*)&S_s[(w * 16 + lm) * 72 + 32 + q4 * 8];
#pragma unroll
    for (int ni = 0; ni < 4; ni++) {
      bf16x8 b0 = *(const bf16x8*)&vT_s[(ni * 16 + lm) * 72 + q4 * 8];
      bf16x8 b1 = *(const bf16x8*)&vT_s[(ni * 16 + lm) * 72 + 32 + q4 * 8];
      f32x4 acc = {0.f, 0.f, 0.f, 0.f};
      acc = __builtin_amdgcn_mfma_f32_16x16x32_bf16(a0, b0, acc, 0, 0, 0);
      acc = __builtin_amdgcn_mfma_f32_16x16x32_bf16(a1, b1, acc, 0, 0, 0);
#pragma unroll
      for (int j = 0; j < 4; j++) {
        int p = w * 16 + q4 * 4 + j;
        int i = ni * 16 + lm;
        intra_bf[rowbase + (size_t)p * 1024 + i] = f2bf(acc[j]);
      }
    }
  }

  // Phase 3: U = (v * g_w)^T @ wk
  {
    bf16x8 a0 = *(const bf16x8*)&vT_s[(w * 16 + lm) * 72 + q4 * 8];
    bf16x8 a1 = *(const bf16x8*)&vT_s[(w * 16 + lm) * 72 + 32 + q4 * 8];
#pragma unroll
    for (int jj = 0; jj < 8; jj++) {
      int p0 = q4 * 8 + jj;
      a0[jj] = (__bf16)((float)a0[jj] * __expf(lg * (float)(63 - p0)));
      a1[jj] = (__bf16)((float)a1[jj] * __expf(lg * (float)(63 - (p0 + 32))));
    }
    size_t ub = ((size_t)bh * 64 + c) * 4096;
#pragma unroll
    for (int nj = 0; nj < 4; nj++) {
      bf16x8 b0 = *(const bf16x8*)&wkT_s[(nj * 16 + lm) * 72 + q4 * 8];
      bf16x8 b1 = *(const bf16x8*)&wkT_s[(nj * 16 + lm) * 72 + 32 + q4 * 8];
      f32x4 acc = {0.f, 0.f, 0.f, 0.f};
      acc = __builtin_amdgcn_mfma_f32_16x16x32_bf16(a0, b0, acc, 0, 0, 0);
      acc = __builtin_amdgcn_mfma_f32_16x16x32_bf16(a1, b1, acc, 0, 0, 0);
#pragma unroll
      for (int j = 0; j < 4; j++) {
        int i = w * 16 + q4 * 4 + j;
        int col = nj * 16 + lm;
        U_bf[ub + i * 64 + col] = f2bf(acc[j]);
      }
    }
  }
}

// ---------------------------------------------------------------- fused scan + inter + combine
// grid (sp=4, bh=64), 256 thr. Block sp owns W rows i in [sp*16, sp*16+16).
// fp32 state in regs (4/thread, exact recurrence). Per chunk c:
//   inter[tok][i] = g_p[tok] * sum_j rk[tok][j] * W_c[i][j]   (NT MFMA, M=64,N=16,K=64)
//   reads = alpha*(inter + intra);  W <- gC*W + U_c.
// Replaces scan_matmul + inter_combine; kills the Wst HBM round-trip (64 MB).
__global__ __launch_bounds__(256) void scan_inter(
    const unsigned short* __restrict__ rkg, const unsigned short* __restrict__ U_bf,
    const unsigned short* __restrict__ intra_bf,
    const float* __restrict__ decay, const float* __restrict__ log_alpha,
    unsigned short* __restrict__ reads_bf) {
  int sp = blockIdx.x, bh = blockIdx.y;
  int b = bh >> 4, h = bh & 15;
  int tid = threadIdx.x, l = tid & 63, w = tid >> 6;
  int lm = l & 15, q4 = l >> 4;
  float gamma = 1.0f / (1.0f + __expf(-decay[h]));
  float lg = __logf(gamma);
  float gC = __expf(64.0f * lg);
  float alpha = __expf(log_alpha[h]);
  int i0 = sp * 16;

  __shared__ unsigned short rk_s[64 * 72];
  __shared__ unsigned short W_s[16 * 72];

  // thread's state slice: local flat idx tid*4 of 16x64 block -> lrow=tid>>4, col=(tid&15)*4
  int lrow = tid >> 4, colb = (tid & 15) * 4;
  float Wreg[4] = {0.f, 0.f, 0.f, 0.f};

  int p_a = tid >> 3, seg_a = (tid & 7) * 8;       // rk staging rows (tokens 0..31 / 32..63)
  const size_t bbase = (size_t)b * 4096 * 1024 + h * 64;
  size_t ubase = (size_t)bh * 64 * 4096;

  // prefetch chunk 0
  uint4 nrk0 = *(const uint4*)(rkg + bbase + (size_t)p_a * 1024 + seg_a);
  uint4 nrk1 = *(const uint4*)(rkg + bbase + (size_t)(p_a + 32) * 1024 + seg_a);
  ushort4 nu = *(const ushort4*)(U_bf + ubase + (i0 + lrow) * 64 + colb);

  for (int c = 0; c < 64; c++) {
    uint4 rk0 = nrk0, rk1 = nrk1;
    ushort4 uc = nu;
    __syncthreads();  // LDS readers of chunk c-1 done; prefetched loads drained here
    *(uint4*)&rk_s[p_a * 72 + seg_a] = rk0;
    *(uint4*)&rk_s[(p_a + 32) * 72 + seg_a] = rk1;
    {
      ushort4 wv;
      wv.x = f2bf(Wreg[0]); wv.y = f2bf(Wreg[1]); wv.z = f2bf(Wreg[2]); wv.w = f2bf(Wreg[3]);
      *(ushort4*)&W_s[lrow * 72 + colb] = wv;
    }
    __syncthreads();
    if (c + 1 < 64) {  // prefetch chunk c+1; drains at next top-barrier after full phase
      size_t nrb = bbase + (size_t)(c + 1) * 64 * 1024;
      nrk0 = *(const uint4*)(rkg + nrb + (size_t)p_a * 1024 + seg_a);
      nrk1 = *(const uint4*)(rkg + nrb + (size_t)(p_a + 32) * 1024 + seg_a);
      nu = *(const ushort4*)(U_bf + ubase + (size_t)(c + 1) * 4096 + (i0 + lrow) * 64 + colb);
    }
    // MFMA: wave w covers tokens w*16..w*16+16; N=16 (our i-rows); K=64 in 2 steps
    f32x4 acc = {0.f, 0.f, 0.f, 0.f};
#pragma unroll
    for (int kst = 0; kst < 2; kst++) {
      bf16x8 a = *(const bf16x8*)&rk_s[(w * 16 + lm) * 72 + kst * 32 + q4 * 8];
      bf16x8 bb = *(const bf16x8*)&W_s[lm * 72 + kst * 32 + q4 * 8];
      acc = __builtin_amdgcn_mfma_f32_16x16x32_bf16(a, bb, acc, 0, 0, 0);
    }
    // epilogue: token = w*16 + q4*4 + j (position within chunk), col = i0 + lm
    size_t rowbase = bbase + (size_t)c * 64 * 1024;
#pragma unroll
    for (int j = 0; j < 4; j++) {
      int ptok = w * 16 + q4 * 4 + j;
      float gp = __expf(lg * (float)ptok);
      size_t ad = rowbase + (size_t)ptok * 1024 + i0 + lm;
      reads_bf[ad] = f2bf(alpha * (acc[j] * gp + bf2f(intra_bf[ad])));
    }
    // state update (exact fp32): W <- gC*W + U_c
    Wreg[0] = gC * Wreg[0] + bf2f(uc.x);
    Wreg[1] = gC * Wreg[1] + bf2f(uc.y);
    Wreg[2] = gC * Wreg[2] + bf2f(uc.z);
    Wreg[3] = gC * Wreg[3] + bf2f(uc.w);
  }
}

// ----------------------------------------------------------------
extern "C" void kernel_launch(void* const* d_in, const int* in_sizes, int n_in,
                              void* d_out, int out_size, void* d_ws, size_t ws_size,
                              hipStream_t stream) {
  const float* out_f = (const float*)d_in[0];
  const float* Ww = (const float*)d_in[1];
  const float* Wr = (const float*)d_in[2];
  const float* decay = (const float*)d_in[3];
  const float* lalpha = (const float*)d_in[4];

  char* ws = (char*)d_ws;
  unsigned short* outbf = (unsigned short*)(ws + 0);
  unsigned short* vbf   = (unsigned short*)(ws + 33554432);
  unsigned short* wwbf  = (unsigned short*)(ws + 67108864);  // wrbf adjacent at +2MB
  unsigned short* wrbf  = (unsigned short*)(ws + 69206016);
  unsigned short* intra = (unsigned short*)(ws + 71303168);
  unsigned short* U     = (unsigned short*)(ws + 104857600);
  unsigned short* reads = (unsigned short*)(ws + 171966464);

  cast_f32_to_bf16<<<dim3(8192), 256, 0, stream>>>(out_f, outbf, 16777216 / 8);
  cast_weights<<<dim3(1024), 256, 0, stream>>>(Ww, Wr, wwbf);

  // V = out @ W_write^T   (M=B*T=16384, N=D=1024, K=D=1024)
  gemm_bt_bf16out<<<dim3(1024), 256, 0, stream>>>(outbf, wwbf, vbf, 16384, 1024, 1024);

  chunk_local<<<dim3(64, 64), 256, 0, stream>>>(outbf, vbf, decay, intra, U);
  scan_inter<<<dim3(4, 64), 256, 0, stream>>>(outbf, U, intra, decay, lalpha, reads);

  // final = out + reads @ W_read^T (base added from bf16 copy)
  gemm_bt_addout<<<dim3(1024), 256, 0, stream>>>(reads, wrbf, outbf, (float*)d_out,
                                                 16384, 1024, 1024);
}